// Round 1
// baseline (295.329 us; speedup 1.0000x reference)
//
#include <hip/hip_runtime.h>
#include <hip/hip_bf16.h>

typedef __attribute__((ext_vector_type(8))) short short8;
typedef __attribute__((ext_vector_type(4))) float f32x4;

#define BQ 8
#define SEQ 4096
#define CH 512
#define NHD 8
#define HD 64
#define K3C 1536
#define MTOK 32768
#define NSPL 8

__device__ __forceinline__ float bfu2f(unsigned int u) {
  u <<= 16;
  float f;
  __builtin_memcpy(&f, &u, 4);
  return f;
}
__device__ __forceinline__ unsigned short f2bfu(float x) {
  __hip_bfloat16 h = __float2bfloat16(x);
  unsigned short u;
  __builtin_memcpy(&u, &h, 2);
  return u;
}
__device__ __forceinline__ void unpack8(const uint4 u, float* dst) {
  dst[0] = bfu2f(u.x & 0xffffu); dst[1] = bfu2f(u.x >> 16);
  dst[2] = bfu2f(u.y & 0xffffu); dst[3] = bfu2f(u.y >> 16);
  dst[4] = bfu2f(u.z & 0xffffu); dst[5] = bfu2f(u.z >> 16);
  dst[6] = bfu2f(u.w & 0xffffu); dst[7] = bfu2f(u.w >> 16);
}

__device__ __forceinline__ void gload_lds16(const void* g, void* l) {
  __builtin_amdgcn_global_load_lds(
      (const __attribute__((address_space(1))) unsigned int*)g,
      (__attribute__((address_space(3))) unsigned int*)l, 16, 0, 0);
}

// ---------------- cast kernels ----------------
__global__ __launch_bounds__(256) void cast_f32_bf16(const float* __restrict__ in,
                                                     unsigned short* __restrict__ out, int n4) {
  int stride = gridDim.x * blockDim.x;
  for (int i = blockIdx.x * blockDim.x + threadIdx.x; i < n4; i += stride) {
    float4 v = reinterpret_cast<const float4*>(in)[i];
    ushort4 o;
    o.x = f2bfu(v.x); o.y = f2bfu(v.y); o.z = f2bfu(v.z); o.w = f2bfu(v.w);
    reinterpret_cast<ushort4*>(out)[i] = o;
  }
}

// in: f32 [R][Cc] row-major -> out: bf16 [Cc][R]
__global__ __launch_bounds__(256) void transpose_cast(const float* __restrict__ in,
                                                      unsigned short* __restrict__ out,
                                                      int R, int Cc) {
  __shared__ float tile[32][33];
  const int tx = threadIdx.x, ty = threadIdx.y;  // 32 x 8
  const int c0 = blockIdx.x * 32, r0 = blockIdx.y * 32;
  #pragma unroll
  for (int dy = 0; dy < 32; dy += 8)
    tile[ty + dy][tx] = in[(size_t)(r0 + ty + dy) * Cc + (c0 + tx)];
  __syncthreads();
  #pragma unroll
  for (int dy = 0; dy < 32; dy += 8)
    out[(size_t)(c0 + ty + dy) * R + (r0 + tx)] = f2bfu(tile[tx][ty + dy]);
}

// ---------------- bf16 MFMA GEMM: C = A[M][K] * Bt[N][K]^T ----------------
template <bool OUT_BF16>
__global__ __launch_bounds__(256) void gemm_bt(const unsigned short* __restrict__ A,
                                               const unsigned short* __restrict__ Bt,
                                               void* __restrict__ Cout,
                                               const float* __restrict__ bias,
                                               int M, int Nn, int Kk) {
  __shared__ unsigned short As[128 * 32];
  __shared__ unsigned short Bs[128 * 32];
  const int tid = threadIdx.x;
  const int wave = tid >> 6, lane = tid & 63;
  const int m0 = blockIdx.y * 128, n0 = blockIdx.x * 128;
  const int wr = wave >> 1, wc = wave & 1;
  f32x4 acc[4][4] = {};

  for (int k0 = 0; k0 < Kk; k0 += 32) {
    __syncthreads();
    #pragma unroll
    for (int j = 0; j < 2; ++j) {
      const int ch = wave * 2 + j;
      const int e = ch * 512 + lane * 8;   // bf16 element index in 128x32 tile
      const int r = e >> 5, c = e & 31;
      gload_lds16(A + (size_t)(m0 + r) * Kk + (k0 + c), &As[ch * 512]);
      gload_lds16(Bt + (size_t)(n0 + r) * Kk + (k0 + c), &Bs[ch * 512]);
    }
    asm volatile("s_waitcnt vmcnt(0)" ::: "memory");
    __syncthreads();

    const int lg = (lane >> 4) * 8, l15 = lane & 15;
    short8 af[4], bfr[4];
    #pragma unroll
    for (int i = 0; i < 4; ++i)
      af[i] = *reinterpret_cast<const short8*>(&As[(wr * 64 + i * 16 + l15) * 32 + lg]);
    #pragma unroll
    for (int j = 0; j < 4; ++j)
      bfr[j] = *reinterpret_cast<const short8*>(&Bs[(wc * 64 + j * 16 + l15) * 32 + lg]);
    #pragma unroll
    for (int i = 0; i < 4; ++i)
      #pragma unroll
      for (int j = 0; j < 4; ++j)
        acc[i][j] = __builtin_amdgcn_mfma_f32_16x16x32_bf16(af[i], bfr[j], acc[i][j], 0, 0, 0);
  }

  const int lr = (lane >> 4) * 4, lc = lane & 15;
  #pragma unroll
  for (int i = 0; i < 4; ++i) {
    #pragma unroll
    for (int j = 0; j < 4; ++j) {
      const int mr = m0 + wr * 64 + i * 16 + lr;
      const int nc = n0 + wc * 64 + j * 16 + lc;
      #pragma unroll
      for (int v = 0; v < 4; ++v) {
        const float val = acc[i][j][v];
        if (OUT_BF16) {
          reinterpret_cast<unsigned short*>(Cout)[(size_t)(mr + v) * Nn + nc] = f2bfu(val);
        } else {
          reinterpret_cast<float*>(Cout)[(size_t)(mr + v) * Nn + nc] = val + bias[nc];
        }
      }
    }
  }
}

// ---------------- attention partials: raw q.kT and sumsq norms ----------------
__global__ __launch_bounds__(256) void attn_partial(const unsigned short* __restrict__ qkv,
                                                    float* __restrict__ rawp,
                                                    float* __restrict__ normp) {
  const int blk = blockIdx.x;
  const int bh = blk >> 3, s = blk & 7;
  const int b = bh >> 3, h = bh & 7;
  __shared__ float QL[64][68];
  __shared__ float KL[64][68];
  const int tid = threadIdx.x;
  const int tx = tid & 15, ty = tid >> 4;
  float racc[4][4] = {};
  float sq[4] = {0.f, 0.f, 0.f, 0.f}, sk[4] = {0.f, 0.f, 0.f, 0.f};

  for (int chunk = 0; chunk < 8; ++chunk) {
    const int nbase = b * SEQ + s * 512 + chunk * 64;
    __syncthreads();
    #pragma unroll
    for (int l = 0; l < 2; ++l) {
      const int cidx = tid * 2 + l;
      const int r = cidx >> 3, off = (cidx & 7) * 8;
      const size_t rowoff = (size_t)(nbase + r) * K3C;
      uint4 uq = *reinterpret_cast<const uint4*>(qkv + rowoff + h * 64 + off);
      uint4 uk = *reinterpret_cast<const uint4*>(qkv + rowoff + 512 + h * 64 + off);
      unpack8(uq, &QL[r][off]);
      unpack8(uk, &KL[r][off]);
    }
    __syncthreads();
    for (int n = 0; n < 64; ++n) {
      float4 qv = *reinterpret_cast<const float4*>(&QL[n][ty * 4]);
      float4 kv = *reinterpret_cast<const float4*>(&KL[n][tx * 4]);
      float qa[4] = {qv.x, qv.y, qv.z, qv.w};
      float ka[4] = {kv.x, kv.y, kv.z, kv.w};
      #pragma unroll
      for (int i = 0; i < 4; ++i)
        #pragma unroll
        for (int j = 0; j < 4; ++j)
          racc[i][j] = fmaf(qa[i], ka[j], racc[i][j]);
      if (tx == 0) {
        #pragma unroll
        for (int i = 0; i < 4; ++i) sq[i] = fmaf(qa[i], qa[i], sq[i]);
      }
      if (ty == 0) {
        #pragma unroll
        for (int j = 0; j < 4; ++j) sk[j] = fmaf(ka[j], ka[j], sk[j]);
      }
    }
  }
  float* rp = rawp + ((size_t)s * 64 + bh) * 4096;
  #pragma unroll
  for (int i = 0; i < 4; ++i)
    #pragma unroll
    for (int j = 0; j < 4; ++j)
      rp[(ty * 4 + i) * 64 + tx * 4 + j] = racc[i][j];
  float* np = normp + ((size_t)s * 64 + bh) * 128;
  if (tx == 0) {
    #pragma unroll
    for (int i = 0; i < 4; ++i) np[ty * 4 + i] = sq[i];
  }
  if (ty == 0) {
    #pragma unroll
    for (int j = 0; j < 4; ++j) np[64 + tx * 4 + j] = sk[j];
  }
}

// ---------------- finalize: reduce partials, normalize, softmax ----------------
__global__ __launch_bounds__(64) void attn_finalize(const float* __restrict__ rawp,
                                                    const float* __restrict__ normp,
                                                    const float* __restrict__ temperature,
                                                    unsigned short* __restrict__ attnP) {
  const int bh = blockIdx.x, h = bh & 7;
  const int d = threadIdx.x;
  float nq = 0.f, nk = 0.f;
  for (int s = 0; s < NSPL; ++s) {
    nq += normp[((size_t)s * 64 + bh) * 128 + d];
    nk += normp[((size_t)s * 64 + bh) * 128 + 64 + d];
  }
  nq = fmaxf(sqrtf(nq), 1e-12f);
  nk = fmaxf(sqrtf(nk), 1e-12f);
  const float t = temperature[h];
  for (int c = 0; c < 64; ++c) {
    float r = 0.f;
    for (int s = 0; s < NSPL; ++s)
      r += rawp[((size_t)s * 64 + bh) * 4096 + c * 64 + d];
    const float nqc = __shfl(nq, c);
    float v = r * t / (nqc * nk);
    float m = v;
    #pragma unroll
    for (int off = 32; off > 0; off >>= 1) m = fmaxf(m, __shfl_xor(m, off));
    float e = __expf(v - m);
    float ssum = e;
    #pragma unroll
    for (int off = 32; off > 0; off >>= 1) ssum += __shfl_xor(ssum, off);
    attnP[(size_t)bh * 4096 + c * 64 + d] = f2bfu(e / ssum);
  }
}

// ---------------- y[n][h*64+c] = sum_d P[c][d] * V[n][d] ----------------
__global__ __launch_bounds__(256) void pv_kernel(const unsigned short* __restrict__ qkv,
                                                 const unsigned short* __restrict__ attnP,
                                                 unsigned short* __restrict__ y) {
  const int nt = blockIdx.x, h = blockIdx.y, b = blockIdx.z;
  const int bh = b * 8 + h;
  __shared__ float PL[64][68];
  __shared__ float VL[64][68];
  const int tid = threadIdx.x;
  const int tx = tid & 15, ty = tid >> 4;
  #pragma unroll
  for (int l = 0; l < 2; ++l) {
    const int cidx = tid * 2 + l;
    const int r = cidx >> 3, off = (cidx & 7) * 8;
    uint4 up = *reinterpret_cast<const uint4*>(attnP + (size_t)bh * 4096 + r * 64 + off);
    uint4 uv = *reinterpret_cast<const uint4*>(
        qkv + (size_t)(b * SEQ + nt * 64 + r) * K3C + 1024 + h * 64 + off);
    unpack8(up, &PL[r][off]);
    unpack8(uv, &VL[r][off]);
  }
  __syncthreads();
  float acc[4][4] = {};
  for (int d4 = 0; d4 < 64; d4 += 4) {
    float4 vv[4], pp[4];
    #pragma unroll
    for (int i = 0; i < 4; ++i) vv[i] = *reinterpret_cast<const float4*>(&VL[ty * 4 + i][d4]);
    #pragma unroll
    for (int j = 0; j < 4; ++j) pp[j] = *reinterpret_cast<const float4*>(&PL[tx * 4 + j][d4]);
    #pragma unroll
    for (int i = 0; i < 4; ++i)
      #pragma unroll
      for (int j = 0; j < 4; ++j)
        acc[i][j] += vv[i].x * pp[j].x + vv[i].y * pp[j].y + vv[i].z * pp[j].z + vv[i].w * pp[j].w;
  }
  #pragma unroll
  for (int i = 0; i < 4; ++i) {
    ushort4 o;
    o.x = f2bfu(acc[i][0]); o.y = f2bfu(acc[i][1]);
    o.z = f2bfu(acc[i][2]); o.w = f2bfu(acc[i][3]);
    *reinterpret_cast<ushort4*>(
        &y[(size_t)(b * SEQ + nt * 64 + ty * 4 + i) * CH + h * 64 + tx * 4]) = o;
  }
}

extern "C" void kernel_launch(void* const* d_in, const int* in_sizes, int n_in,
                              void* d_out, int out_size, void* d_ws, size_t ws_size,
                              hipStream_t stream) {
  const float* x = (const float*)d_in[0];
  const float* Wqkv = (const float*)d_in[2];
  const float* temp = (const float*)d_in[3];
  const float* Wproj = (const float*)d_in[4];
  const float* bproj = (const float*)d_in[5];
  float* out = (float*)d_out;

  char* w = (char*)d_ws;
  unsigned short* xb = (unsigned short*)w;    w += (size_t)MTOK * CH * 2;
  unsigned short* wqT = (unsigned short*)w;   w += (size_t)K3C * CH * 2;
  unsigned short* wpT = (unsigned short*)w;   w += (size_t)CH * CH * 2;
  unsigned short* qkvb = (unsigned short*)w;  w += (size_t)MTOK * K3C * 2;
  unsigned short* yb = (unsigned short*)w;    w += (size_t)MTOK * CH * 2;
  float* rawp = (float*)w;                    w += (size_t)NSPL * 64 * 4096 * 4;
  float* normp = (float*)w;                   w += (size_t)NSPL * 64 * 128 * 4;
  unsigned short* attnP = (unsigned short*)w; w += (size_t)64 * 4096 * 2;

  cast_f32_bf16<<<2048, 256, 0, stream>>>(x, xb, MTOK * CH / 4);
  transpose_cast<<<dim3(K3C / 32, CH / 32), dim3(32, 8), 0, stream>>>(Wqkv, wqT, CH, K3C);
  transpose_cast<<<dim3(CH / 32, CH / 32), dim3(32, 8), 0, stream>>>(Wproj, wpT, CH, CH);
  gemm_bt<true><<<dim3(K3C / 128, MTOK / 128), 256, 0, stream>>>(xb, wqT, qkvb, nullptr,
                                                                 MTOK, K3C, CH);
  attn_partial<<<512, 256, 0, stream>>>(qkvb, rawp, normp);
  attn_finalize<<<64, 64, 0, stream>>>(rawp, normp, temp, attnP);
  pv_kernel<<<dim3(SEQ / 64, NHD, BQ), 256, 0, stream>>>(qkvb, attnP, yb);
  gemm_bt<false><<<dim3(CH / 128, MTOK / 128), 256, 0, stream>>>(yb, wpT, out, bproj,
                                                                 MTOK, CH, CH);
}

// Round 2
// 272.812 us; speedup vs baseline: 1.0825x; 1.0825x over previous
//
#include <hip/hip_runtime.h>
#include <hip/hip_bf16.h>

typedef __attribute__((ext_vector_type(8))) short short8;
typedef __attribute__((ext_vector_type(4))) float f32x4;

#define BQ 8
#define SEQ 4096
#define CH 512
#define NHD 8
#define HD 64
#define K3C 1536
#define MTOK 32768
#define NSPL 8

__device__ __forceinline__ float bfu2f(unsigned int u) {
  u <<= 16;
  float f;
  __builtin_memcpy(&f, &u, 4);
  return f;
}
__device__ __forceinline__ unsigned short f2bfu(float x) {
  __hip_bfloat16 h = __float2bfloat16(x);
  unsigned short u;
  __builtin_memcpy(&u, &h, 2);
  return u;
}
__device__ __forceinline__ void unpack8(const uint4 u, float* dst) {
  dst[0] = bfu2f(u.x & 0xffffu); dst[1] = bfu2f(u.x >> 16);
  dst[2] = bfu2f(u.y & 0xffffu); dst[3] = bfu2f(u.y >> 16);
  dst[4] = bfu2f(u.z & 0xffffu); dst[5] = bfu2f(u.z >> 16);
  dst[6] = bfu2f(u.w & 0xffffu); dst[7] = bfu2f(u.w >> 16);
}

__device__ __forceinline__ void gload_lds16(const void* g, void* l) {
  __builtin_amdgcn_global_load_lds(
      (const __attribute__((address_space(1))) unsigned int*)g,
      (__attribute__((address_space(3))) unsigned int*)l, 16, 0, 0);
}

// ---------------- cast kernels ----------------
__global__ __launch_bounds__(256) void cast_f32_bf16(const float* __restrict__ in,
                                                     unsigned short* __restrict__ out, int n4) {
  int stride = gridDim.x * blockDim.x;
  for (int i = blockIdx.x * blockDim.x + threadIdx.x; i < n4; i += stride) {
    float4 v = reinterpret_cast<const float4*>(in)[i];
    ushort4 o;
    o.x = f2bfu(v.x); o.y = f2bfu(v.y); o.z = f2bfu(v.z); o.w = f2bfu(v.w);
    reinterpret_cast<ushort4*>(out)[i] = o;
  }
}

// in: f32 [R][Cc] row-major -> out: bf16 [Cc][R]
__global__ __launch_bounds__(256) void transpose_cast(const float* __restrict__ in,
                                                      unsigned short* __restrict__ out,
                                                      int R, int Cc) {
  __shared__ float tile[32][33];
  const int tx = threadIdx.x, ty = threadIdx.y;  // 32 x 8
  const int c0 = blockIdx.x * 32, r0 = blockIdx.y * 32;
  #pragma unroll
  for (int dy = 0; dy < 32; dy += 8)
    tile[ty + dy][tx] = in[(size_t)(r0 + ty + dy) * Cc + (c0 + tx)];
  __syncthreads();
  #pragma unroll
  for (int dy = 0; dy < 32; dy += 8)
    out[(size_t)(c0 + ty + dy) * R + (r0 + tx)] = f2bfu(tile[tx][ty + dy]);
}

// ---------------- 256x256 tile, BK=64, counted-vmcnt 4-phase MFMA GEMM ----------------
// C = A[M][K] * Bt[N][K]^T.  LDS: dbuf x (A 256x64 + B 256x64) bf16 = 128 KB.
// Swizzled LDS layout: byte(row,k) = row*128 + (((k>>3) ^ (row&7))<<4) + (k&7)*2.
// Stage (global_load_lds, linear dest): lane l covers row rbase+(l>>3), slot l&7;
//   pre-swizzled global src col = ((l&7)^(l>>3))*8  (rbase % 8 == 0).
// Phase q of K-tile t: compute (A-half q>>1) x (B-half q&1), stage half q of tile t+1.
// Half stage order A0,B0,B1,A1 vs first-use distances {4,3,3,3} phases -> vmcnt(6) safe.
template <bool OUT_BF16>
__global__ __launch_bounds__(512, 2) void gemm256(const unsigned short* __restrict__ A,
                                                  const unsigned short* __restrict__ Bt,
                                                  void* __restrict__ Cout,
                                                  const float* __restrict__ bias,
                                                  int M, int Nn, int Kk, int nbx) {
  __shared__ __align__(16) char lds[131072];
  const int nwg = gridDim.x;
  int wg = blockIdx.x;
  wg = (wg & 7) * (nwg >> 3) + (wg >> 3);  // XCD swizzle (nwg % 8 == 0)
  const int bx = wg % nbx, by = wg / nbx;
  const int m0 = by * 256, n0 = bx * 256;

  const int tid = threadIdx.x, wave = tid >> 6, lane = tid & 63;
  const int wr = wave >> 2, wc = wave & 3;
  const int l15 = lane & 15, lg = lane >> 4;
  const int T = Kk >> 6;

  f32x4 acc[2][4][2][2] = {};

  auto stageh = [&](int h, int kt, char* buf) {
    const bool isB = (h == 1 || h == 2);
    const unsigned short* src = isB ? Bt : A;
    const int rc0 = isB ? n0 : m0;
    const int rhalf = (h >= 2) ? 128 : 0;
    char* base = buf + (isB ? 32768 : 0);
    #pragma unroll
    for (int j = 0; j < 2; ++j) {
      const int rbase = rhalf + (wave * 2 + j) * 8;
      const unsigned short* g = src + (size_t)(rc0 + rbase + (lane >> 3)) * Kk + kt +
                                (((lane & 7) ^ (lane >> 3)) << 3);
      gload_lds16(g, base + rbase * 128);
    }
  };

  auto comp = [&](int q, const char* bufc) {
    const char* bA = bufc;
    const char* bB = bufc + 32768;
    const int qa = q >> 1, qb = q & 1;
    short8 af[4][2], bfv[2][2];
    #pragma unroll
    for (int fr = 0; fr < 4; ++fr)
      #pragma unroll
      for (int ks = 0; ks < 2; ++ks) {
        const int r = wr * 64 + qa * 128 + fr * 16 + l15;
        const int slot = ((ks << 2) + lg) ^ (r & 7);
        af[fr][ks] = *reinterpret_cast<const short8*>(bA + r * 128 + (slot << 4));
      }
    #pragma unroll
    for (int fc = 0; fc < 2; ++fc)
      #pragma unroll
      for (int ks = 0; ks < 2; ++ks) {
        const int n = wc * 32 + qb * 128 + fc * 16 + l15;
        const int slot = ((ks << 2) + lg) ^ (n & 7);
        bfv[fc][ks] = *reinterpret_cast<const short8*>(bB + n * 128 + (slot << 4));
      }
    asm volatile("s_waitcnt lgkmcnt(0)" ::: "memory");
    __builtin_amdgcn_s_setprio(1);
    #pragma unroll
    for (int fr = 0; fr < 4; ++fr)
      #pragma unroll
      for (int fc = 0; fc < 2; ++fc)
        #pragma unroll
        for (int ks = 0; ks < 2; ++ks)
          acc[qa][fr][qb][fc] = __builtin_amdgcn_mfma_f32_16x16x32_bf16(
              af[fr][ks], bfv[fc][ks], acc[qa][fr][qb][fc], 0, 0, 0);
    __builtin_amdgcn_s_setprio(0);
  };

  // prologue: all 4 halves of K-tile 0 into buf0
  stageh(0, 0, lds);
  stageh(1, 0, lds);
  stageh(2, 0, lds);
  stageh(3, 0, lds);

  for (int t = 0; t < T - 1; ++t) {
    char* bufc = lds + ((t & 1) << 16);
    char* bufn = lds + (((t + 1) & 1) << 16);
    const int ktn = (t + 1) << 6;
    #pragma unroll
    for (int q = 0; q < 4; ++q) {
      stageh(q, ktn, bufn);
      asm volatile("s_waitcnt vmcnt(6)" ::: "memory");
      __builtin_amdgcn_s_barrier();
      comp(q, bufc);
    }
  }

  // last K-tile: drain once, then compute all 4 phases (no stage -> no barriers)
  asm volatile("s_waitcnt vmcnt(0)" ::: "memory");
  __builtin_amdgcn_s_barrier();
  {
    const char* bufc = lds + (((T - 1) & 1) << 16);
    #pragma unroll
    for (int q = 0; q < 4; ++q) comp(q, bufc);
  }

  // epilogue
  #pragma unroll
  for (int qa = 0; qa < 2; ++qa)
    #pragma unroll
    for (int fr = 0; fr < 4; ++fr)
      #pragma unroll
      for (int qb = 0; qb < 2; ++qb)
        #pragma unroll
        for (int fc = 0; fc < 2; ++fc) {
          const int row0 = m0 + wr * 64 + qa * 128 + fr * 16 + lg * 4;
          const int col = n0 + wc * 32 + qb * 128 + fc * 16 + l15;
          #pragma unroll
          for (int v = 0; v < 4; ++v) {
            const float val = acc[qa][fr][qb][fc][v];
            if (OUT_BF16) {
              reinterpret_cast<unsigned short*>(Cout)[(size_t)(row0 + v) * Nn + col] = f2bfu(val);
            } else {
              reinterpret_cast<float*>(Cout)[(size_t)(row0 + v) * Nn + col] = val + bias[col];
            }
          }
        }
}

// ---------------- attention partials: raw q.kT and sumsq norms ----------------
__global__ __launch_bounds__(256) void attn_partial(const unsigned short* __restrict__ qkv,
                                                    float* __restrict__ rawp,
                                                    float* __restrict__ normp) {
  const int blk = blockIdx.x;
  const int bh = blk >> 3, s = blk & 7;
  const int b = bh >> 3, h = bh & 7;
  __shared__ float QL[64][68];
  __shared__ float KL[64][68];
  const int tid = threadIdx.x;
  const int tx = tid & 15, ty = tid >> 4;
  float racc[4][4] = {};
  float sq[4] = {0.f, 0.f, 0.f, 0.f}, sk[4] = {0.f, 0.f, 0.f, 0.f};

  for (int chunk = 0; chunk < 8; ++chunk) {
    const int nbase = b * SEQ + s * 512 + chunk * 64;
    __syncthreads();
    #pragma unroll
    for (int l = 0; l < 2; ++l) {
      const int cidx = tid * 2 + l;
      const int r = cidx >> 3, off = (cidx & 7) * 8;
      const size_t rowoff = (size_t)(nbase + r) * K3C;
      uint4 uq = *reinterpret_cast<const uint4*>(qkv + rowoff + h * 64 + off);
      uint4 uk = *reinterpret_cast<const uint4*>(qkv + rowoff + 512 + h * 64 + off);
      unpack8(uq, &QL[r][off]);
      unpack8(uk, &KL[r][off]);
    }
    __syncthreads();
    for (int n = 0; n < 64; ++n) {
      float4 qv = *reinterpret_cast<const float4*>(&QL[n][ty * 4]);
      float4 kv = *reinterpret_cast<const float4*>(&KL[n][tx * 4]);
      float qa[4] = {qv.x, qv.y, qv.z, qv.w};
      float ka[4] = {kv.x, kv.y, kv.z, kv.w};
      #pragma unroll
      for (int i = 0; i < 4; ++i)
        #pragma unroll
        for (int j = 0; j < 4; ++j)
          racc[i][j] = fmaf(qa[i], ka[j], racc[i][j]);
      if (tx == 0) {
        #pragma unroll
        for (int i = 0; i < 4; ++i) sq[i] = fmaf(qa[i], qa[i], sq[i]);
      }
      if (ty == 0) {
        #pragma unroll
        for (int j = 0; j < 4; ++j) sk[j] = fmaf(ka[j], ka[j], sk[j]);
      }
    }
  }
  float* rp = rawp + ((size_t)s * 64 + bh) * 4096;
  #pragma unroll
  for (int i = 0; i < 4; ++i)
    #pragma unroll
    for (int j = 0; j < 4; ++j)
      rp[(ty * 4 + i) * 64 + tx * 4 + j] = racc[i][j];
  float* np = normp + ((size_t)s * 64 + bh) * 128;
  if (tx == 0) {
    #pragma unroll
    for (int i = 0; i < 4; ++i) np[ty * 4 + i] = sq[i];
  }
  if (ty == 0) {
    #pragma unroll
    for (int j = 0; j < 4; ++j) np[64 + tx * 4 + j] = sk[j];
  }
}

// ---------------- finalize: reduce partials, normalize, softmax ----------------
__global__ __launch_bounds__(64) void attn_finalize(const float* __restrict__ rawp,
                                                    const float* __restrict__ normp,
                                                    const float* __restrict__ temperature,
                                                    unsigned short* __restrict__ attnP) {
  const int bh = blockIdx.x, h = bh & 7;
  const int d = threadIdx.x;
  float nq = 0.f, nk = 0.f;
  for (int s = 0; s < NSPL; ++s) {
    nq += normp[((size_t)s * 64 + bh) * 128 + d];
    nk += normp[((size_t)s * 64 + bh) * 128 + 64 + d];
  }
  nq = fmaxf(sqrtf(nq), 1e-12f);
  nk = fmaxf(sqrtf(nk), 1e-12f);
  const float t = temperature[h];
  for (int c = 0; c < 64; ++c) {
    float r = 0.f;
    for (int s = 0; s < NSPL; ++s)
      r += rawp[((size_t)s * 64 + bh) * 4096 + c * 64 + d];
    const float nqc = __shfl(nq, c);
    float v = r * t / (nqc * nk);
    float m = v;
    #pragma unroll
    for (int off = 32; off > 0; off >>= 1) m = fmaxf(m, __shfl_xor(m, off));
    float e = __expf(v - m);
    float ssum = e;
    #pragma unroll
    for (int off = 32; off > 0; off >>= 1) ssum += __shfl_xor(ssum, off);
    attnP[(size_t)bh * 4096 + c * 64 + d] = f2bfu(e / ssum);
  }
}

// ---------------- y[n][h*64+c] = sum_d P[c][d] * V[n][d] ----------------
__global__ __launch_bounds__(256) void pv_kernel(const unsigned short* __restrict__ qkv,
                                                 const unsigned short* __restrict__ attnP,
                                                 unsigned short* __restrict__ y) {
  const int nt = blockIdx.x, h = blockIdx.y, b = blockIdx.z;
  const int bh = b * 8 + h;
  __shared__ float PL[64][68];
  __shared__ float VL[64][68];
  const int tid = threadIdx.x;
  const int tx = tid & 15, ty = tid >> 4;
  #pragma unroll
  for (int l = 0; l < 2; ++l) {
    const int cidx = tid * 2 + l;
    const int r = cidx >> 3, off = (cidx & 7) * 8;
    uint4 up = *reinterpret_cast<const uint4*>(attnP + (size_t)bh * 4096 + r * 64 + off);
    uint4 uv = *reinterpret_cast<const uint4*>(
        qkv + (size_t)(b * SEQ + nt * 64 + r) * K3C + 1024 + h * 64 + off);
    unpack8(up, &PL[r][off]);
    unpack8(uv, &VL[r][off]);
  }
  __syncthreads();
  float acc[4][4] = {};
  for (int d4 = 0; d4 < 64; d4 += 4) {
    float4 vv[4], pp[4];
    #pragma unroll
    for (int i = 0; i < 4; ++i) vv[i] = *reinterpret_cast<const float4*>(&VL[ty * 4 + i][d4]);
    #pragma unroll
    for (int j = 0; j < 4; ++j) pp[j] = *reinterpret_cast<const float4*>(&PL[tx * 4 + j][d4]);
    #pragma unroll
    for (int i = 0; i < 4; ++i)
      #pragma unroll
      for (int j = 0; j < 4; ++j)
        acc[i][j] += vv[i].x * pp[j].x + vv[i].y * pp[j].y + vv[i].z * pp[j].z + vv[i].w * pp[j].w;
  }
  #pragma unroll
  for (int i = 0; i < 4; ++i) {
    ushort4 o;
    o.x = f2bfu(acc[i][0]); o.y = f2bfu(acc[i][1]);
    o.z = f2bfu(acc[i][2]); o.w = f2bfu(acc[i][3]);
    *reinterpret_cast<ushort4*>(
        &y[(size_t)(b * SEQ + nt * 64 + ty * 4 + i) * CH + h * 64 + tx * 4]) = o;
  }
}

extern "C" void kernel_launch(void* const* d_in, const int* in_sizes, int n_in,
                              void* d_out, int out_size, void* d_ws, size_t ws_size,
                              hipStream_t stream) {
  const float* x = (const float*)d_in[0];
  const float* Wqkv = (const float*)d_in[2];
  const float* temp = (const float*)d_in[3];
  const float* Wproj = (const float*)d_in[4];
  const float* bproj = (const float*)d_in[5];
  float* out = (float*)d_out;

  char* w = (char*)d_ws;
  unsigned short* xb = (unsigned short*)w;    w += (size_t)MTOK * CH * 2;
  unsigned short* wqT = (unsigned short*)w;   w += (size_t)K3C * CH * 2;
  unsigned short* wpT = (unsigned short*)w;   w += (size_t)CH * CH * 2;
  unsigned short* qkvb = (unsigned short*)w;  w += (size_t)MTOK * K3C * 2;
  unsigned short* yb = (unsigned short*)w;    w += (size_t)MTOK * CH * 2;
  float* rawp = (float*)w;                    w += (size_t)NSPL * 64 * 4096 * 4;
  float* normp = (float*)w;                   w += (size_t)NSPL * 64 * 128 * 4;
  unsigned short* attnP = (unsigned short*)w; w += (size_t)64 * 4096 * 2;

  cast_f32_bf16<<<2048, 256, 0, stream>>>(x, xb, MTOK * CH / 4);
  transpose_cast<<<dim3(K3C / 32, CH / 32), dim3(32, 8), 0, stream>>>(Wqkv, wqT, CH, K3C);
  transpose_cast<<<dim3(CH / 32, CH / 32), dim3(32, 8), 0, stream>>>(Wproj, wpT, CH, CH);
  gemm256<true><<<768, 512, 0, stream>>>(xb, wqT, qkvb, nullptr, MTOK, K3C, CH, 6);
  attn_partial<<<512, 256, 0, stream>>>(qkvb, rawp, normp);
  attn_finalize<<<64, 64, 0, stream>>>(rawp, normp, temp, attnP);
  pv_kernel<<<dim3(SEQ / 64, NHD, BQ), 256, 0, stream>>>(qkvb, attnP, yb);
  gemm256<false><<<256, 512, 0, stream>>>(yb, wpT, out, bproj, MTOK, CH, CH, 2);
}